// Round 1
// baseline (568.551 us; speedup 1.0000x reference)
//
#include <hip/hip_runtime.h>

// ---------------------------------------------------------------------------
// Attention_42674795053784 : cross-attention forward on MI355X (gfx950)
//   b=4, n=m=2048, DIM=1024, NH=16, HD=64
//   out = softmax( rope(rms(Q)) rope(rms(K))^T / 8 ) V  @ Wo
// Round 1: full bf16-MFMA pipeline, correctness-first.
// ---------------------------------------------------------------------------

typedef __bf16 bf16_t;
typedef __bf16 bf16x8 __attribute__((ext_vector_type(8)));
typedef float  f32x4  __attribute__((ext_vector_type(4)));

#define DIMM   1024
#define NHEAD  16
#define HDIM   64
#define NB     4
#define SEQ    2048
#define NROWS  (NB * SEQ)             // 8192
#define RMS_EPS 1.1920929e-07f
#define LOG2_10000_DIV32 0.4152410118609203f

// --------------------------------------------------------------------------
// Weight transpose + fp32->bf16: Wt[n][k] = (bf16) W[k][n]
// --------------------------------------------------------------------------
__global__ __launch_bounds__(256)
void transpose_w(const float* __restrict__ W, bf16_t* __restrict__ Wt,
                 int K, int N)
{
    __shared__ float t[32][33];
    const int n0 = blockIdx.x * 32;
    const int k0 = blockIdx.y * 32;
    const int tx = threadIdx.x & 31;
    const int ty = threadIdx.x >> 5;       // 0..7
#pragma unroll
    for (int i = ty; i < 32; i += 8)
        t[i][tx] = W[(size_t)(k0 + i) * N + n0 + tx];
    __syncthreads();
#pragma unroll
    for (int i = ty; i < 32; i += 8)
        Wt[(size_t)(n0 + i) * K + k0 + tx] = (bf16_t)t[tx][i];
}

// --------------------------------------------------------------------------
// 128x128 tile MFMA GEMM:  C[M][N] = A[M][K] * Bt[N][K]^T
//   A: fp32 (cast to bf16 during staging) or bf16.  Bt always bf16 [N][K].
//   Out: bf16 or fp32.  M,N,K multiples of 128/128/64.  256 thr = 4 waves,
//   each wave 64x64 via 4x4 grid of 16x16x32 bf16 MFMAs.
//   LDS row stride 72 bf16 (144 B = 36 words): fragment reads (quad*8 pattern)
//   and staging writes both land 8 words/bank -> conflict-free b128.
// --------------------------------------------------------------------------
template<bool A_F32, bool OUT_BF16>
__global__ __launch_bounds__(256)
void gemm128(const void* __restrict__ Ap, const bf16_t* __restrict__ Bt,
             void* __restrict__ Cp, int M, int N, int K)
{
    __shared__ bf16_t As[128][72];
    __shared__ bf16_t Bs[128][72];

    const int bm   = blockIdx.y * 128;
    const int bn   = blockIdx.x * 128;
    const int tid  = threadIdx.x;
    const int lane = tid & 63;
    const int wave = tid >> 6;
    const int wm   = (wave >> 1) * 64;
    const int wn   = (wave & 1) * 64;
    const int lr   = lane & 15;
    const int quad = lane >> 4;

    const int sr = tid >> 1;          // staging row 0..127
    const int sh = tid & 1;           // staging col half (32 elems each)

    f32x4 zero4 = {0.f, 0.f, 0.f, 0.f};
    f32x4 acc[4][4];
#pragma unroll
    for (int i = 0; i < 4; ++i)
#pragma unroll
        for (int j = 0; j < 4; ++j) acc[i][j] = zero4;

    for (int k0 = 0; k0 < K; k0 += 64) {
        // ---- stage A tile (128 x 64) ----
        if (A_F32) {
            const float* a = (const float*)Ap + (size_t)(bm + sr) * K + k0 + sh * 32;
            float4 f[8];
#pragma unroll
            for (int i = 0; i < 8; ++i) f[i] = ((const float4*)a)[i];
            bf16_t cv[32];
            const float* fs = (const float*)&f[0];
#pragma unroll
            for (int i = 0; i < 32; ++i) cv[i] = (bf16_t)fs[i];
#pragma unroll
            for (int i = 0; i < 4; ++i)
                *(int4*)&As[sr][sh * 32 + 8 * i] = ((const int4*)cv)[i];
        } else {
            const bf16_t* a = (const bf16_t*)Ap + (size_t)(bm + sr) * K + k0 + sh * 32;
#pragma unroll
            for (int i = 0; i < 4; ++i)
                *(int4*)&As[sr][sh * 32 + 8 * i] = ((const int4*)a)[i];
        }
        // ---- stage B tile (128 x 64) ----
        {
            const bf16_t* bsrc = Bt + (size_t)(bn + sr) * K + k0 + sh * 32;
#pragma unroll
            for (int i = 0; i < 4; ++i)
                *(int4*)&Bs[sr][sh * 32 + 8 * i] = ((const int4*)bsrc)[i];
        }
        __syncthreads();

#pragma unroll
        for (int ks = 0; ks < 2; ++ks) {
            bf16x8 af[4], bfr[4];
#pragma unroll
            for (int i = 0; i < 4; ++i)
                af[i] = *(const bf16x8*)&As[wm + i * 16 + lr][ks * 32 + quad * 8];
#pragma unroll
            for (int j = 0; j < 4; ++j)
                bfr[j] = *(const bf16x8*)&Bs[wn + j * 16 + lr][ks * 32 + quad * 8];
#pragma unroll
            for (int i = 0; i < 4; ++i)
#pragma unroll
                for (int j = 0; j < 4; ++j)
                    acc[i][j] = __builtin_amdgcn_mfma_f32_16x16x32_bf16(
                        af[i], bfr[j], acc[i][j], 0, 0, 0);
        }
        __syncthreads();
    }

    // ---- epilogue: C/D layout col=lane&15, row=quad*4+reg (HW-verified) ----
#pragma unroll
    for (int i = 0; i < 4; ++i)
#pragma unroll
        for (int j = 0; j < 4; ++j) {
            const int r0 = bm + wm + i * 16 + quad * 4;
            const int c  = bn + wn + j * 16 + lr;
#pragma unroll
            for (int rg = 0; rg < 4; ++rg) {
                const float v = acc[i][j][rg];
                if (OUT_BF16)
                    ((bf16_t*)Cp)[(size_t)(r0 + rg) * N + c] = (bf16_t)v;
                else
                    ((float*)Cp)[(size_t)(r0 + rg) * N + c] = v;
            }
        }
}

// --------------------------------------------------------------------------
// Per-head RMSNorm + RoPE.  One wave per (token-row, head); lane = d index.
//   X: bf16 [8192][ldx] proj output; out: bf16 [b, h, seq, 64]
// --------------------------------------------------------------------------
__global__ __launch_bounds__(256)
void norm_rope(const bf16_t* __restrict__ X, int ldx,
               const int* __restrict__ pos, const float* __restrict__ w,
               bf16_t* __restrict__ outp)
{
    const int lane = threadIdx.x & 63;
    const int wv   = threadIdx.x >> 6;
    const int gid  = blockIdx.x * 4 + wv;   // 0 .. 8192*16-1
    const int row  = gid >> 4;              // 0..8191  (= b*2048 + s)
    const int head = gid & 15;
    const int bb   = row >> 11;
    const int ss_i = row & 2047;

    float x = (float)X[(size_t)row * ldx + head * HDIM + lane];
    float ss = x * x;
#pragma unroll
    for (int off = 32; off; off >>= 1) ss += __shfl_xor(ss, off, 64);
    float xn = x * rsqrtf(ss * (1.f / 64.f) + RMS_EPS) * w[lane];

    const int p = pos[row];
    const int j = lane & 31;
    const float inv_freq = exp2f(-(float)j * LOG2_10000_DIV32);  // 10000^(-j/32)
    const float ang = (float)p * inv_freq;
    float sv, cv;
    sincosf(ang, &sv, &cv);
    const float other = __shfl_xor(xn, 32, 64);
    const float res = (lane < 32) ? (xn * cv - other * sv)
                                  : (xn * cv + other * sv);
    outp[((size_t)(bb * NHEAD + head) * SEQ + ss_i) * HDIM + lane] = (bf16_t)res;
}

// --------------------------------------------------------------------------
// V transpose: KVp[b*2048+m][1024 + h*64 + d]  ->  vT[(b,h)][d][m]
// --------------------------------------------------------------------------
__global__ __launch_bounds__(256)
void v_trans(const bf16_t* __restrict__ KVp, bf16_t* __restrict__ vT)
{
    __shared__ bf16_t t[64][65];
    const int m0 = blockIdx.x * 64;
    const int h  = blockIdx.y;
    const int b  = blockIdx.z;
    const int r  = threadIdx.x >> 2;   // 0..63
    const int cg = threadIdx.x & 3;    // 16-elem chunk

    const bf16_t* src = KVp + (size_t)(b * SEQ + m0 + r) * (2 * DIMM)
                        + DIMM + h * HDIM + cg * 16;
    bf16_t tmp[16];
    *(int4*)&tmp[0] = ((const int4*)src)[0];
    *(int4*)&tmp[8] = ((const int4*)src)[1];
#pragma unroll
    for (int i = 0; i < 16; ++i) t[r][cg * 16 + i] = tmp[i];
    __syncthreads();
#pragma unroll
    for (int i = 0; i < 16; ++i) tmp[i] = t[cg * 16 + i][r];
    bf16_t* dst = vT + ((size_t)(b * NHEAD + h) * HDIM + r) * SEQ + m0 + cg * 16;
    ((int4*)dst)[0] = *(int4*)&tmp[0];
    ((int4*)dst)[1] = *(int4*)&tmp[8];
}

// --------------------------------------------------------------------------
// Flash attention.  Block = 64 q-rows of one (b,h); 4 waves x 16 rows.
//   q [bh][n][64], k [bh][m][64], vT [bh][64][m] -> x [b][n][h*64] bf16
//   S-tile per wave: 16x64 via 8 MFMAs; online softmax in C/D layout
//   (row = quad*4+reg -> row reduction = 16-lane shuffle); P -> wave-private
//   LDS -> A-layout; PV: 8 MFMAs against Vs (Vt chunk, contiguous in m).
// --------------------------------------------------------------------------
__global__ __launch_bounds__(256)
void attn(const bf16_t* __restrict__ q, const bf16_t* __restrict__ k,
          const bf16_t* __restrict__ vT, bf16_t* __restrict__ xo)
{
    __shared__ bf16_t Ks[64][72];
    __shared__ bf16_t Vs[64][72];
    __shared__ bf16_t Ps[4][16][72];

    const int q0   = blockIdx.x * 64;
    const int h    = blockIdx.y;
    const int b    = blockIdx.z;
    const int bh   = b * NHEAD + h;
    const int tid  = threadIdx.x;
    const int lane = tid & 63;
    const int wv   = tid >> 6;
    const int lr   = lane & 15;
    const int quad = lane >> 4;

    // Q fragments (A-layout: m=lane&15, k=quad*8+j), 2 k-steps of 32
    bf16x8 aq[2];
    {
        const bf16_t* qb = q + ((size_t)bh * SEQ + q0 + wv * 16 + lr) * HDIM;
        aq[0] = *(const bf16x8*)(qb + quad * 8);
        aq[1] = *(const bf16x8*)(qb + 32 + quad * 8);
    }

    f32x4 zero4 = {0.f, 0.f, 0.f, 0.f};
    f32x4 o[4];
    float mi[4], li[4];
#pragma unroll
    for (int r = 0; r < 4; ++r) {
        o[r] = zero4; mi[r] = -__builtin_inff(); li[r] = 0.f;
    }

    const int sr = tid >> 2, cg = tid & 3;
    const bf16_t* kb = k  + (size_t)bh * SEQ * HDIM;
    const bf16_t* vb = vT + (size_t)bh * HDIM * SEQ;

    for (int m0 = 0; m0 < SEQ; m0 += 64) {
        // stage K chunk [m][d] and Vt chunk [d][m]
        {
            const bf16_t* ksrc = kb + (size_t)(m0 + sr) * HDIM + cg * 16;
            int4 u0 = ((const int4*)ksrc)[0];
            int4 u1 = ((const int4*)ksrc)[1];
            const bf16_t* vsrc = vb + (size_t)sr * SEQ + m0 + cg * 16;
            int4 w0 = ((const int4*)vsrc)[0];
            int4 w1 = ((const int4*)vsrc)[1];
            *(int4*)&Ks[sr][cg * 16]     = u0;
            *(int4*)&Ks[sr][cg * 16 + 8] = u1;
            *(int4*)&Vs[sr][cg * 16]     = w0;
            *(int4*)&Vs[sr][cg * 16 + 8] = w1;
        }
        __syncthreads();

        // S = Q * Kchunk^T  (16 x 64 per wave)
        f32x4 s[4];
#pragma unroll
        for (int j = 0; j < 4; ++j) s[j] = zero4;
#pragma unroll
        for (int ks = 0; ks < 2; ++ks)
#pragma unroll
            for (int j = 0; j < 4; ++j) {
                bf16x8 bk = *(const bf16x8*)&Ks[j * 16 + lr][ks * 32 + quad * 8];
                s[j] = __builtin_amdgcn_mfma_f32_16x16x32_bf16(aq[ks], bk, s[j], 0, 0, 0);
            }

        // online softmax; lane holds rows quad*4+r, cols j*16+lr
#pragma unroll
        for (int r = 0; r < 4; ++r) {
            float mx = fmaxf(fmaxf(s[0][r], s[1][r]), fmaxf(s[2][r], s[3][r]));
#pragma unroll
            for (int off = 1; off < 16; off <<= 1)
                mx = fmaxf(mx, __shfl_xor(mx, off, 64));
            const float mnew  = fmaxf(mi[r], mx * 0.125f);
            const float alpha = __expf(mi[r] - mnew);
            float rs = 0.f;
#pragma unroll
            for (int j = 0; j < 4; ++j) {
                const float p = __expf(s[j][r] * 0.125f - mnew);
                s[j][r] = p;
                rs += p;
            }
#pragma unroll
            for (int off = 1; off < 16; off <<= 1) rs += __shfl_xor(rs, off, 64);
            li[r] = li[r] * alpha + rs;
            mi[r] = mnew;
#pragma unroll
            for (int j = 0; j < 4; ++j) o[j][r] *= alpha;
        }

        // P (C/D layout) -> wave-private LDS -> A-layout (in-wave, no barrier)
#pragma unroll
        for (int j = 0; j < 4; ++j)
#pragma unroll
            for (int r = 0; r < 4; ++r)
                Ps[wv][quad * 4 + r][j * 16 + lr] = (bf16_t)s[j][r];

#pragma unroll
        for (int ks = 0; ks < 2; ++ks) {
            bf16x8 ap = *(const bf16x8*)&Ps[wv][lr][ks * 32 + quad * 8];
#pragma unroll
            for (int j = 0; j < 4; ++j) {
                bf16x8 bv = *(const bf16x8*)&Vs[j * 16 + lr][ks * 32 + quad * 8];
                o[j] = __builtin_amdgcn_mfma_f32_16x16x32_bf16(ap, bv, o[j], 0, 0, 0);
            }
        }
        __syncthreads();
    }

    // epilogue: x[b][q][h*64+d]
#pragma unroll
    for (int r = 0; r < 4; ++r) li[r] = 1.f / li[r];
#pragma unroll
    for (int j = 0; j < 4; ++j)
#pragma unroll
        for (int r = 0; r < 4; ++r) {
            const size_t row = (size_t)b * SEQ + q0 + wv * 16 + quad * 4 + r;
            xo[row * DIMM + h * HDIM + j * 16 + lr] = (bf16_t)(o[j][r] * li[r]);
        }
}

// --------------------------------------------------------------------------
extern "C" void kernel_launch(void* const* d_in, const int* in_sizes, int n_in,
                              void* d_out, int out_size, void* d_ws, size_t ws_size,
                              hipStream_t stream)
{
    const float* tgt  = (const float*)d_in[0];
    const float* src  = (const float*)d_in[1];
    const int*   tpos = (const int*)d_in[2];
    const int*   spos = (const int*)d_in[3];
    const float* Wq   = (const float*)d_in[4];
    const float* Wkv  = (const float*)d_in[5];
    const float* Wo   = (const float*)d_in[6];
    const float* qw   = (const float*)d_in[7];
    const float* kw   = (const float*)d_in[8];
    float* out = (float*)d_out;

    // workspace layout (120 MB total)
    char* ws = (char*)d_ws;
    const size_t MB = 1024 * 1024;
    bf16_t* Wq_t  = (bf16_t*)(ws + 0 * MB);    // [1024][1024]   2 MB
    bf16_t* Wkv_t = (bf16_t*)(ws + 2 * MB);    // [2048][1024]   4 MB
    bf16_t* Wo_t  = (bf16_t*)(ws + 6 * MB);    // [1024][1024]   2 MB
    bf16_t* Qp    = (bf16_t*)(ws + 8 * MB);    // [8192][1024]  16 MB
    bf16_t* KVp   = (bf16_t*)(ws + 24 * MB);   // [8192][2048]  32 MB
    bf16_t* qb    = (bf16_t*)(ws + 56 * MB);   // [b,h,n,64]    16 MB
    bf16_t* kbuf  = (bf16_t*)(ws + 72 * MB);   // [b,h,m,64]    16 MB
    bf16_t* vT    = (bf16_t*)(ws + 88 * MB);   // [b,h,64,m]    16 MB
    bf16_t* xb    = (bf16_t*)(ws + 104 * MB);  // [b,n,1024]    16 MB

    // weight transposes (fp32 -> bf16, [K][N] -> [N][K])
    transpose_w<<<dim3(32, 32), 256, 0, stream>>>(Wq,  Wq_t,  1024, 1024);
    transpose_w<<<dim3(64, 32), 256, 0, stream>>>(Wkv, Wkv_t, 1024, 2048);
    transpose_w<<<dim3(32, 32), 256, 0, stream>>>(Wo,  Wo_t,  1024, 1024);

    // projections (fp32 A cast in staging, bf16 out)
    gemm128<true, true><<<dim3(8, 64),  256, 0, stream>>>(tgt, Wq_t,  Qp,  NROWS, 1024, 1024);
    gemm128<true, true><<<dim3(16, 64), 256, 0, stream>>>(src, Wkv_t, KVp, NROWS, 2048, 1024);

    // rmsnorm + rope + layout
    norm_rope<<<32768, 256, 0, stream>>>(Qp,  1024, tpos, qw, qb);
    norm_rope<<<32768, 256, 0, stream>>>(KVp, 2048, spos, kw, kbuf);
    v_trans<<<dim3(32, NHEAD, NB), 256, 0, stream>>>(KVp, vT);

    // flash attention
    attn<<<dim3(32, NHEAD, NB), 256, 0, stream>>>(qb, kbuf, vT, xb);

    // output projection (bf16 A, fp32 out)
    gemm128<false, false><<<dim3(8, 64), 256, 0, stream>>>(xb, Wo_t, out, NROWS, 1024, 1024);
}

// Round 2
// 426.534 us; speedup vs baseline: 1.3330x; 1.3330x over previous
//
#include <hip/hip_runtime.h>

// ---------------------------------------------------------------------------
// Attention_42674795053784 : cross-attention forward on MI355X (gfx950)
// R2: fixed-max softmax (||q||=||k||=8 bound -> no online max/rescale),
//     32 q-rows/wave attn, m97-style GEMMs (global_load_lds w16 + XOR swizzle)
// ---------------------------------------------------------------------------

typedef __bf16 bf16_t;
typedef __bf16 bf16x8 __attribute__((ext_vector_type(8)));
typedef float  f32x4  __attribute__((ext_vector_type(4)));

#define DIMM   1024
#define NHEAD  16
#define HDIM   64
#define NB     4
#define SEQ    2048
#define NROWS  (NB * SEQ)             // 8192
#define RMS_EPS 1.1920929e-07f
#define LOG2_10000_DIV32 0.4152410118609203f

// async global->LDS, 16B per lane; lds dest = base + lane*16 (wave-uniform base)
__device__ __forceinline__ void async16(const bf16_t* g, bf16_t* l) {
    __builtin_amdgcn_global_load_lds(
        (const __attribute__((address_space(1))) void*)g,
        (__attribute__((address_space(3))) void*)l, 16, 0, 0);
}

// --------------------------------------------------------------------------
// fp32 -> bf16 elementwise cast (8 elems/thread)
// --------------------------------------------------------------------------
__global__ __launch_bounds__(256)
void cast_bf16(const float* __restrict__ x, bf16_t* __restrict__ y)
{
    const size_t i = ((size_t)blockIdx.x * 256 + threadIdx.x) * 8;
    float4 f0 = ((const float4*)(x + i))[0];
    float4 f1 = ((const float4*)(x + i))[1];
    bf16_t v[8];
    v[0] = (bf16_t)f0.x; v[1] = (bf16_t)f0.y; v[2] = (bf16_t)f0.z; v[3] = (bf16_t)f0.w;
    v[4] = (bf16_t)f1.x; v[5] = (bf16_t)f1.y; v[6] = (bf16_t)f1.z; v[7] = (bf16_t)f1.w;
    *(int4*)(y + i) = *(int4*)v;
}

// --------------------------------------------------------------------------
// Weight transpose + fp32->bf16: Wt[n][k] = (bf16) W[k][n]
// --------------------------------------------------------------------------
__global__ __launch_bounds__(256)
void transpose_w(const float* __restrict__ W, bf16_t* __restrict__ Wt,
                 int K, int N)
{
    __shared__ float t[32][33];
    const int n0 = blockIdx.x * 32;
    const int k0 = blockIdx.y * 32;
    const int tx = threadIdx.x & 31;
    const int ty = threadIdx.x >> 5;
#pragma unroll
    for (int i = ty; i < 32; i += 8)
        t[i][tx] = W[(size_t)(k0 + i) * N + n0 + tx];
    __syncthreads();
#pragma unroll
    for (int i = ty; i < 32; i += 8)
        Wt[(size_t)(n0 + i) * K + k0 + tx] = (bf16_t)t[tx][i];
}

// --------------------------------------------------------------------------
// m97-style 128x128 MFMA GEMM: C[M][N] = A[M][K] * Bt[N][K]^T, A/B bf16.
//   global_load_lds width16 staging; LDS rows stride 64 bf16 (unpadded),
//   8-elem k-groups XOR-swizzled: group g of row r lives at slot g^(r&7).
//   Frag reads stay ds_read_b128 and bank-balanced (8 slots x 8 lanes).
// --------------------------------------------------------------------------
template<bool OUT_BF16>
__global__ __launch_bounds__(256)
void gemm128(const bf16_t* __restrict__ A, const bf16_t* __restrict__ Bt,
             void* __restrict__ Cp, int M, int N, int K)
{
    __shared__ bf16_t As[128 * 64];
    __shared__ bf16_t Bs[128 * 64];

    const int bm   = blockIdx.y * 128;
    const int bn   = blockIdx.x * 128;
    const int tid  = threadIdx.x;
    const int lane = tid & 63;
    const int wave = tid >> 6;
    const int wm   = (wave >> 1) * 64;
    const int wn   = (wave & 1) * 64;
    const int lr   = lane & 15;
    const int quad = lane >> 4;
    const int srow = lane >> 3;        // 0..7 within a 1KB (8-row) DMA
    const int sslot= lane & 7;         // 16B slot within row

    size_t aoff[4], boff[4];
    bf16_t *alp[4], *blp[4];
#pragma unroll
    for (int t = 0; t < 4; ++t) {
        const int rb = wave * 32 + t * 8;
        const int r  = rb + srow;
        const int g  = sslot ^ (r & 7);
        aoff[t] = (size_t)(bm + r) * K + g * 8;
        boff[t] = (size_t)(bn + r) * K + g * 8;
        alp[t]  = As + rb * 64;
        blp[t]  = Bs + rb * 64;
    }

    f32x4 zero4 = {0.f, 0.f, 0.f, 0.f};
    f32x4 acc[4][4];
#pragma unroll
    for (int i = 0; i < 4; ++i)
#pragma unroll
        for (int j = 0; j < 4; ++j) acc[i][j] = zero4;

    for (int k0 = 0; k0 < K; k0 += 64) {
#pragma unroll
        for (int t = 0; t < 4; ++t) {
            async16(A  + aoff[t] + k0, alp[t]);
            async16(Bt + boff[t] + k0, blp[t]);
        }
        __syncthreads();

#pragma unroll
        for (int ks = 0; ks < 2; ++ks) {
            bf16x8 af[4], bfr[4];
#pragma unroll
            for (int i = 0; i < 4; ++i)
                af[i] = *(const bf16x8*)&As[(wm + i * 16 + lr) * 64 +
                                            (((ks * 4 + quad) ^ (lr & 7)) * 8)];
#pragma unroll
            for (int j = 0; j < 4; ++j)
                bfr[j] = *(const bf16x8*)&Bs[(wn + j * 16 + lr) * 64 +
                                             (((ks * 4 + quad) ^ (lr & 7)) * 8)];
#pragma unroll
            for (int i = 0; i < 4; ++i)
#pragma unroll
                for (int j = 0; j < 4; ++j)
                    acc[i][j] = __builtin_amdgcn_mfma_f32_16x16x32_bf16(
                        af[i], bfr[j], acc[i][j], 0, 0, 0);
        }
        __syncthreads();
    }

    // C/D layout: col=lane&15, row=quad*4+reg
#pragma unroll
    for (int i = 0; i < 4; ++i)
#pragma unroll
        for (int j = 0; j < 4; ++j) {
            const int r0 = bm + wm + i * 16 + quad * 4;
            const int c  = bn + wn + j * 16 + lr;
#pragma unroll
            for (int rg = 0; rg < 4; ++rg) {
                const float v = acc[i][j][rg];
                if (OUT_BF16)
                    ((bf16_t*)Cp)[(size_t)(r0 + rg) * N + c] = (bf16_t)v;
                else
                    ((float*)Cp)[(size_t)(r0 + rg) * N + c] = v;
            }
        }
}

// --------------------------------------------------------------------------
// Per-head RMSNorm + RoPE (+ output scale).  One wave per (row, head).
// --------------------------------------------------------------------------
__global__ __launch_bounds__(256)
void norm_rope(const bf16_t* __restrict__ X, int ldx,
               const int* __restrict__ pos, const float* __restrict__ w,
               bf16_t* __restrict__ outp, float scale)
{
    const int lane = threadIdx.x & 63;
    const int wv   = threadIdx.x >> 6;
    const int gid  = blockIdx.x * 4 + wv;
    const int row  = gid >> 4;
    const int head = gid & 15;
    const int bb   = row >> 11;
    const int ss_i = row & 2047;

    float x = (float)X[(size_t)row * ldx + head * HDIM + lane];
    float ss = x * x;
#pragma unroll
    for (int off = 32; off; off >>= 1) ss += __shfl_xor(ss, off, 64);
    float xn = x * rsqrtf(ss * (1.f / 64.f) + RMS_EPS) * w[lane];

    const int p = pos[row];
    const int j = lane & 31;
    const float inv_freq = exp2f(-(float)j * LOG2_10000_DIV32);
    const float ang = (float)p * inv_freq;
    float sv, cv;
    sincosf(ang, &sv, &cv);
    const float other = __shfl_xor(xn, 32, 64);
    const float res = (lane < 32) ? (xn * cv - other * sv)
                                  : (xn * cv + other * sv);
    outp[((size_t)(bb * NHEAD + head) * SEQ + ss_i) * HDIM + lane] =
        (bf16_t)(res * scale);
}

// --------------------------------------------------------------------------
// V transpose: KVp[b*2048+m][1024 + h*64 + d] -> vT[(b,h)][d][m]
// --------------------------------------------------------------------------
__global__ __launch_bounds__(256)
void v_trans(const bf16_t* __restrict__ KVp, bf16_t* __restrict__ vT)
{
    __shared__ bf16_t t[64][65];
    const int m0 = blockIdx.x * 64;
    const int h  = blockIdx.y;
    const int b  = blockIdx.z;
    const int r  = threadIdx.x >> 2;
    const int cg = threadIdx.x & 3;

    const bf16_t* src = KVp + (size_t)(b * SEQ + m0 + r) * (2 * DIMM)
                        + DIMM + h * HDIM + cg * 16;
    bf16_t tmp[16];
    *(int4*)&tmp[0] = ((const int4*)src)[0];
    *(int4*)&tmp[8] = ((const int4*)src)[1];
#pragma unroll
    for (int i = 0; i < 16; ++i) t[r][cg * 16 + i] = tmp[i];
    __syncthreads();
#pragma unroll
    for (int i = 0; i < 16; ++i) tmp[i] = t[cg * 16 + i][r];
    bf16_t* dst = vT + ((size_t)(b * NHEAD + h) * HDIM + r) * SEQ + m0 + cg * 16;
    ((int4*)dst)[0] = *(int4*)&tmp[0];
    ((int4*)dst)[1] = *(int4*)&tmp[8];
}

// --------------------------------------------------------------------------
// Flash attention, fixed-max softmax.
//   q pre-scaled by 0.125 -> s = q'.k, |s| <= ~8.1 -> exp(s) safe in fp32.
//   No max tracking / no alpha rescale; per-lane partial row sums reduced
//   once at the end.  Block = 128 q-rows (4 waves x 32 rows, 2 row-tiles).
//   Ks/Vs: global_load_lds + XOR swizzle, stride 64.  Ps stride 72 (16B mult).
// --------------------------------------------------------------------------
__global__ __launch_bounds__(256)
void attn(const bf16_t* __restrict__ q, const bf16_t* __restrict__ k,
          const bf16_t* __restrict__ vT, bf16_t* __restrict__ xo)
{
    __shared__ bf16_t Ks[64 * 64];          // [m-chunk][d], swizzled
    __shared__ bf16_t Vs[64 * 64];          // [d][m-chunk], swizzled
    __shared__ bf16_t Ps[4][2][16][72];     // per-wave, per row-tile

    const int q0   = blockIdx.x * 128;
    const int h    = blockIdx.y;
    const int b    = blockIdx.z;
    const int bh   = b * NHEAD + h;
    const int tid  = threadIdx.x;
    const int lane = tid & 63;
    const int wv   = tid >> 6;
    const int lr   = lane & 15;
    const int quad = lane >> 4;
    const int srow = lane >> 3;
    const int sslot= lane & 7;

    const bf16_t* kb = k  + (size_t)bh * SEQ * HDIM;
    const bf16_t* vb = vT + (size_t)bh * HDIM * SEQ;

    // Q fragments: 2 row-tiles x 2 k-steps (A-layout: m=lr, k=quad*8+j)
    bf16x8 aq[2][2];
#pragma unroll
    for (int t = 0; t < 2; ++t) {
        const bf16_t* qp = q + ((size_t)bh * SEQ + q0 + wv * 32 + t * 16 + lr) * HDIM;
        aq[t][0] = *(const bf16x8*)(qp + quad * 8);
        aq[t][1] = *(const bf16x8*)(qp + 32 + quad * 8);
    }

    // staging descriptors: 2 DMA instrs each for Ks and Vs per wave
    size_t koff[2], voff[2];
    bf16_t *klp[2], *vlp[2];
#pragma unroll
    for (int t = 0; t < 2; ++t) {
        const int rb = wv * 16 + t * 8;
        const int r  = rb + srow;
        const int g  = sslot ^ (r & 7);
        koff[t] = (size_t)r * HDIM + g * 8;
        voff[t] = (size_t)r * SEQ + g * 8;
        klp[t]  = Ks + rb * 64;
        vlp[t]  = Vs + rb * 64;
    }

    f32x4 zero4 = {0.f, 0.f, 0.f, 0.f};
    f32x4 o[2][4];
    float lsum[2][4];
#pragma unroll
    for (int t = 0; t < 2; ++t)
#pragma unroll
        for (int j = 0; j < 4; ++j) {
            o[t][j] = zero4;
            lsum[t][j] = 0.f;
        }

    for (int m0 = 0; m0 < SEQ; m0 += 64) {
#pragma unroll
        for (int t = 0; t < 2; ++t) {
            async16(kb + (size_t)m0 * HDIM + koff[t], klp[t]);
            async16(vb + voff[t] + m0, vlp[t]);
        }
        __syncthreads();

        // S tiles (2 x 16x64) — K frags shared across row-tiles
        f32x4 s0[4], s1[4];
#pragma unroll
        for (int j = 0; j < 4; ++j) { s0[j] = zero4; s1[j] = zero4; }
#pragma unroll
        for (int ks = 0; ks < 2; ++ks)
#pragma unroll
            for (int j = 0; j < 4; ++j) {
                bf16x8 bk = *(const bf16x8*)&Ks[(j * 16 + lr) * 64 +
                                                (((ks * 4 + quad) ^ (lr & 7)) * 8)];
                s0[j] = __builtin_amdgcn_mfma_f32_16x16x32_bf16(aq[0][ks], bk, s0[j], 0, 0, 0);
                s1[j] = __builtin_amdgcn_mfma_f32_16x16x32_bf16(aq[1][ks], bk, s1[j], 0, 0, 0);
            }

        // p = exp(s); per-lane partial sums; store P for PV (no reductions!)
#pragma unroll
        for (int j = 0; j < 4; ++j)
#pragma unroll
            for (int r = 0; r < 4; ++r) {
                const float p0 = __expf(s0[j][r]);
                const float p1 = __expf(s1[j][r]);
                lsum[0][r] += p0;
                lsum[1][r] += p1;
                Ps[wv][0][quad * 4 + r][j * 16 + lr] = (bf16_t)p0;
                Ps[wv][1][quad * 4 + r][j * 16 + lr] = (bf16_t)p1;
            }

        // PV — V frags shared across row-tiles
#pragma unroll
        for (int ks = 0; ks < 2; ++ks) {
            bf16x8 ap0 = *(const bf16x8*)&Ps[wv][0][lr][ks * 32 + quad * 8];
            bf16x8 ap1 = *(const bf16x8*)&Ps[wv][1][lr][ks * 32 + quad * 8];
#pragma unroll
            for (int j = 0; j < 4; ++j) {
                bf16x8 bv = *(const bf16x8*)&Vs[(j * 16 + lr) * 64 +
                                                (((ks * 4 + quad) ^ (lr & 7)) * 8)];
                o[0][j] = __builtin_amdgcn_mfma_f32_16x16x32_bf16(ap0, bv, o[0][j], 0, 0, 0);
                o[1][j] = __builtin_amdgcn_mfma_f32_16x16x32_bf16(ap1, bv, o[1][j], 0, 0, 0);
            }
        }
        __syncthreads();
    }

    // final row-sum reduce across the 16 lanes holding each row
#pragma unroll
    for (int t = 0; t < 2; ++t)
#pragma unroll
        for (int r = 0; r < 4; ++r) {
#pragma unroll
            for (int off = 1; off < 16; off <<= 1)
                lsum[t][r] += __shfl_xor(lsum[t][r], off, 64);
            lsum[t][r] = 1.f / lsum[t][r];
        }

#pragma unroll
    for (int t = 0; t < 2; ++t)
#pragma unroll
        for (int j = 0; j < 4; ++j)
#pragma unroll
            for (int r = 0; r < 4; ++r) {
                const size_t row = (size_t)b * SEQ + q0 + wv * 32 + t * 16 + quad * 4 + r;
                xo[row * DIMM + h * HDIM + j * 16 + lr] =
                    (bf16_t)(o[t][j][r] * lsum[t][r]);
            }
}

// --------------------------------------------------------------------------
extern "C" void kernel_launch(void* const* d_in, const int* in_sizes, int n_in,
                              void* d_out, int out_size, void* d_ws, size_t ws_size,
                              hipStream_t stream)
{
    const float* tgt  = (const float*)d_in[0];
    const float* src  = (const float*)d_in[1];
    const int*   tpos = (const int*)d_in[2];
    const int*   spos = (const int*)d_in[3];
    const float* Wq   = (const float*)d_in[4];
    const float* Wkv  = (const float*)d_in[5];
    const float* Wo   = (const float*)d_in[6];
    const float* qw   = (const float*)d_in[7];
    const float* kw   = (const float*)d_in[8];
    float* out = (float*)d_out;

    // workspace layout — exactly 120 MB with buffer reuse
    char* ws = (char*)d_ws;
    const size_t MB = 1024 * 1024;
    bf16_t* Wq_t  = (bf16_t*)(ws + 0 * MB);    //  2 MB
    bf16_t* Wkv_t = (bf16_t*)(ws + 2 * MB);    //  4 MB
    bf16_t* Wo_t  = (bf16_t*)(ws + 6 * MB);    //  2 MB
    bf16_t* tgtb  = (bf16_t*)(ws + 8 * MB);    // 16 MB (dead after Q gemm)
    bf16_t* qb    = (bf16_t*)(ws + 8 * MB);    //   ... reused for q [b,h,n,64]
    bf16_t* srcb  = (bf16_t*)(ws + 24 * MB);   // 16 MB (dead after KV gemm)
    bf16_t* xb    = (bf16_t*)(ws + 24 * MB);   //   ... reused for attn out
    bf16_t* Qp    = (bf16_t*)(ws + 40 * MB);   // 16 MB
    bf16_t* KVp   = (bf16_t*)(ws + 56 * MB);   // 32 MB
    bf16_t* kbuf  = (bf16_t*)(ws + 88 * MB);   // 16 MB
    bf16_t* vT    = (bf16_t*)(ws + 104 * MB);  // 16 MB

    // fp32 -> bf16 activations
    cast_bf16<<<4096, 256, 0, stream>>>(tgt, tgtb);
    cast_bf16<<<4096, 256, 0, stream>>>(src, srcb);

    // weight transposes (fp32 -> bf16, [K][N] -> [N][K])
    transpose_w<<<dim3(32, 32), 256, 0, stream>>>(Wq,  Wq_t,  1024, 1024);
    transpose_w<<<dim3(64, 32), 256, 0, stream>>>(Wkv, Wkv_t, 1024, 2048);
    transpose_w<<<dim3(32, 32), 256, 0, stream>>>(Wo,  Wo_t,  1024, 1024);

    // projections
    gemm128<true><<<dim3(8, 64),  256, 0, stream>>>(tgtb, Wq_t,  Qp,  NROWS, 1024, 1024);
    gemm128<true><<<dim3(16, 64), 256, 0, stream>>>(srcb, Wkv_t, KVp, NROWS, 2048, 1024);

    // rmsnorm + rope (q gets the 1/sqrt(d) scale folded in)
    norm_rope<<<32768, 256, 0, stream>>>(Qp,  1024, tpos, qw, qb,   0.125f);
    norm_rope<<<32768, 256, 0, stream>>>(KVp, 2048, spos, kw, kbuf, 1.0f);
    v_trans<<<dim3(32, NHEAD, NB), 256, 0, stream>>>(KVp, vT);

    // flash attention (fixed-max softmax)
    attn<<<dim3(16, NHEAD, NB), 256, 0, stream>>>(qb, kbuf, vT, xb);

    // output projection (fp32 out)
    gemm128<false><<<dim3(8, 64), 256, 0, stream>>>(xb, Wo_t, out, NROWS, 1024, 1024);
}

// Round 3
// 371.653 us; speedup vs baseline: 1.5298x; 1.1477x over previous
//
#include <hip/hip_runtime.h>

// ---------------------------------------------------------------------------
// Attention_42674795053784 : cross-attention forward on MI355X (gfx950)
// R3: S^T=K.Q^T / O^T=V^T.P^T register-resident flash attention (no P LDS
//     round-trip), V written m-permuted by the KV-GEMM epilogue (v_trans
//     deleted), m-chunk 128, merged elementwise kernels (7 launches).
// ---------------------------------------------------------------------------

typedef __bf16 bf16_t;
typedef __bf16 bf16x8 __attribute__((ext_vector_type(8)));
typedef float  f32x4  __attribute__((ext_vector_type(4)));

#define DIMM   1024
#define NHEAD  16
#define HDIM   64
#define NB     4
#define SEQ    2048
#define NROWS  (NB * SEQ)             // 8192
#define RMS_EPS 1.1920929e-07f
#define LOG2_10000_DIV32 0.4152410118609203f

// async global->LDS, 16B per lane; lds dest = base + lane*16 (wave-uniform base)
__device__ __forceinline__ void async16(const bf16_t* g, bf16_t* l) {
    __builtin_amdgcn_global_load_lds(
        (const __attribute__((address_space(1))) void*)g,
        (__attribute__((address_space(3))) void*)l, 16, 0, 0);
}

// --------------------------------------------------------------------------
// fp32 -> bf16 cast for tgt and src in one launch (8 elems/thread)
// --------------------------------------------------------------------------
__global__ __launch_bounds__(256)
void cast2(const float* __restrict__ tgt, const float* __restrict__ src,
           bf16_t* __restrict__ tgtb, bf16_t* __restrict__ srcb)
{
    int bid = blockIdx.x;
    const float* x;
    bf16_t* y;
    if (bid < 4096) { x = tgt; y = tgtb; }
    else            { bid -= 4096; x = src; y = srcb; }
    const size_t i = ((size_t)bid * 256 + threadIdx.x) * 8;
    float4 f0 = ((const float4*)(x + i))[0];
    float4 f1 = ((const float4*)(x + i))[1];
    bf16_t v[8];
    v[0] = (bf16_t)f0.x; v[1] = (bf16_t)f0.y; v[2] = (bf16_t)f0.z; v[3] = (bf16_t)f0.w;
    v[4] = (bf16_t)f1.x; v[5] = (bf16_t)f1.y; v[6] = (bf16_t)f1.z; v[7] = (bf16_t)f1.w;
    *(int4*)(y + i) = *(int4*)v;
}

// --------------------------------------------------------------------------
// All three weight transposes (fp32 [K][N] -> bf16 [N][K]) in one launch
// --------------------------------------------------------------------------
__global__ __launch_bounds__(256)
void transpose3(const float* __restrict__ Wq, const float* __restrict__ Wkv,
                const float* __restrict__ Wo, bf16_t* __restrict__ Wq_t,
                bf16_t* __restrict__ Wkv_t, bf16_t* __restrict__ Wo_t)
{
    __shared__ float t[32][33];
    int bid = blockIdx.x;
    const float* W; bf16_t* Wt; int N, nx;
    if (bid < 1024)      { W = Wq;  Wt = Wq_t;  N = 1024; nx = 32; }
    else if (bid < 3072) { bid -= 1024; W = Wkv; Wt = Wkv_t; N = 2048; nx = 64; }
    else                 { bid -= 3072; W = Wo;  Wt = Wo_t;  N = 1024; nx = 32; }
    const int K  = 1024;
    const int n0 = (bid % nx) * 32;
    const int k0 = (bid / nx) * 32;
    const int tx = threadIdx.x & 31;
    const int ty = threadIdx.x >> 5;
#pragma unroll
    for (int i = ty; i < 32; i += 8)
        t[i][tx] = W[(size_t)(k0 + i) * N + n0 + tx];
    __syncthreads();
#pragma unroll
    for (int i = ty; i < 32; i += 8)
        Wt[(size_t)(n0 + i) * K + k0 + tx] = (bf16_t)t[tx][i];
}

// --------------------------------------------------------------------------
// m97-style 128x128 MFMA GEMM (generic epilogue): C = A[M][K] * Bt[N][K]^T
// --------------------------------------------------------------------------
template<bool OUT_BF16>
__global__ __launch_bounds__(256)
void gemm128(const bf16_t* __restrict__ A, const bf16_t* __restrict__ Bt,
             void* __restrict__ Cp, int M, int N, int K)
{
    __shared__ bf16_t As[128 * 64];
    __shared__ bf16_t Bs[128 * 64];

    const int bm   = blockIdx.y * 128;
    const int bn   = blockIdx.x * 128;
    const int tid  = threadIdx.x;
    const int lane = tid & 63;
    const int wave = tid >> 6;
    const int wm   = (wave >> 1) * 64;
    const int wn   = (wave & 1) * 64;
    const int lr   = lane & 15;
    const int quad = lane >> 4;
    const int srow = lane >> 3;
    const int sslot= lane & 7;

    size_t aoff[4], boff[4];
    bf16_t *alp[4], *blp[4];
#pragma unroll
    for (int t = 0; t < 4; ++t) {
        const int rb = wave * 32 + t * 8;
        const int r  = rb + srow;
        const int g  = sslot ^ (r & 7);
        aoff[t] = (size_t)(bm + r) * K + g * 8;
        boff[t] = (size_t)(bn + r) * K + g * 8;
        alp[t]  = As + rb * 64;
        blp[t]  = Bs + rb * 64;
    }

    f32x4 zero4 = {0.f, 0.f, 0.f, 0.f};
    f32x4 acc[4][4];
#pragma unroll
    for (int i = 0; i < 4; ++i)
#pragma unroll
        for (int j = 0; j < 4; ++j) acc[i][j] = zero4;

    for (int k0 = 0; k0 < K; k0 += 64) {
#pragma unroll
        for (int t = 0; t < 4; ++t) {
            async16(A  + aoff[t] + k0, alp[t]);
            async16(Bt + boff[t] + k0, blp[t]);
        }
        __syncthreads();
#pragma unroll
        for (int ks = 0; ks < 2; ++ks) {
            bf16x8 af[4], bfr[4];
#pragma unroll
            for (int i = 0; i < 4; ++i)
                af[i] = *(const bf16x8*)&As[(wm + i * 16 + lr) * 64 +
                                            (((ks * 4 + quad) ^ (lr & 7)) * 8)];
#pragma unroll
            for (int j = 0; j < 4; ++j)
                bfr[j] = *(const bf16x8*)&Bs[(wn + j * 16 + lr) * 64 +
                                             (((ks * 4 + quad) ^ (lr & 7)) * 8)];
#pragma unroll
            for (int i = 0; i < 4; ++i)
#pragma unroll
                for (int j = 0; j < 4; ++j)
                    acc[i][j] = __builtin_amdgcn_mfma_f32_16x16x32_bf16(
                        af[i], bfr[j], acc[i][j], 0, 0, 0);
        }
        __syncthreads();
    }

    // C/D layout: col=lane&15, row=quad*4+reg
#pragma unroll
    for (int i = 0; i < 4; ++i)
#pragma unroll
        for (int j = 0; j < 4; ++j) {
            const int r0 = bm + wm + i * 16 + quad * 4;
            const int c  = bn + wn + j * 16 + lr;
#pragma unroll
            for (int rg = 0; rg < 4; ++rg) {
                const float v = acc[i][j][rg];
                if (OUT_BF16)
                    ((bf16_t*)Cp)[(size_t)(r0 + rg) * N + c] = (bf16_t)v;
                else
                    ((float*)Cp)[(size_t)(r0 + rg) * N + c] = v;
            }
        }
}

// --------------------------------------------------------------------------
// KV GEMM: same main loop, special epilogue.
//   cols <1024  -> K proj, written compact to Kp [8192][1024] bf16
//   cols >=1024 -> V proj, written DIRECTLY to vT [(b,h)][d][m'] with the
//   PV m-permutation: m = c*128 + ksm*32 + bit4*16 + quad*4 + r lives at
//   p = c*128 + (ksm*4+quad)*8 + bit4*4 + r  -> 4 regs contiguous, 8B stores.
// --------------------------------------------------------------------------
__global__ __launch_bounds__(256)
void gemm_kv(const bf16_t* __restrict__ A, const bf16_t* __restrict__ Bt,
             bf16_t* __restrict__ Kp, bf16_t* __restrict__ vT)
{
    __shared__ bf16_t As[128 * 64];
    __shared__ bf16_t Bs[128 * 64];
    const int K = 1024, N = 2048;

    const int bm   = blockIdx.y * 128;
    const int bn   = blockIdx.x * 128;
    const int tid  = threadIdx.x;
    const int lane = tid & 63;
    const int wave = tid >> 6;
    const int wm   = (wave >> 1) * 64;
    const int wn   = (wave & 1) * 64;
    const int lr   = lane & 15;
    const int quad = lane >> 4;
    const int srow = lane >> 3;
    const int sslot= lane & 7;

    size_t aoff[4], boff[4];
    bf16_t *alp[4], *blp[4];
#pragma unroll
    for (int t = 0; t < 4; ++t) {
        const int rb = wave * 32 + t * 8;
        const int r  = rb + srow;
        const int g  = sslot ^ (r & 7);
        aoff[t] = (size_t)(bm + r) * K + g * 8;
        boff[t] = (size_t)(bn + r) * K + g * 8;
        alp[t]  = As + rb * 64;
        blp[t]  = Bs + rb * 64;
    }

    f32x4 zero4 = {0.f, 0.f, 0.f, 0.f};
    f32x4 acc[4][4];
#pragma unroll
    for (int i = 0; i < 4; ++i)
#pragma unroll
        for (int j = 0; j < 4; ++j) acc[i][j] = zero4;

    for (int k0 = 0; k0 < K; k0 += 64) {
#pragma unroll
        for (int t = 0; t < 4; ++t) {
            async16(A  + aoff[t] + k0, alp[t]);
            async16(Bt + boff[t] + k0, blp[t]);
        }
        __syncthreads();
#pragma unroll
        for (int ks = 0; ks < 2; ++ks) {
            bf16x8 af[4], bfr[4];
#pragma unroll
            for (int i = 0; i < 4; ++i)
                af[i] = *(const bf16x8*)&As[(wm + i * 16 + lr) * 64 +
                                            (((ks * 4 + quad) ^ (lr & 7)) * 8)];
#pragma unroll
            for (int j = 0; j < 4; ++j)
                bfr[j] = *(const bf16x8*)&Bs[(wn + j * 16 + lr) * 64 +
                                             (((ks * 4 + quad) ^ (lr & 7)) * 8)];
#pragma unroll
            for (int i = 0; i < 4; ++i)
#pragma unroll
                for (int j = 0; j < 4; ++j)
                    acc[i][j] = __builtin_amdgcn_mfma_f32_16x16x32_bf16(
                        af[i], bfr[j], acc[i][j], 0, 0, 0);
        }
        __syncthreads();
    }

#pragma unroll
    for (int i = 0; i < 4; ++i) {
        const int M0 = bm + wm + i * 16;             // 16-aligned row base
        const int b  = M0 >> 11;
        const int mB = M0 & 2047;                    // token index base
        // m-permutation components (uniform over quad/rg except quad term)
        const int chunkbase = mB & ~127;
        const int ksm  = (mB >> 5) & 3;
        const int bit4 = (mB >> 4) & 1;
        const int pbase = (ksm * 4 + quad) * 8 + bit4 * 4;
#pragma unroll
        for (int j = 0; j < 4; ++j) {
            const int c = bn + wn + j * 16 + lr;
            if (c < 1024) {
#pragma unroll
                for (int rg = 0; rg < 4; ++rg)
                    Kp[(size_t)(M0 + quad * 4 + rg) * 1024 + c] =
                        (bf16_t)acc[i][j][rg];
            } else {
                const int h = (c - 1024) >> 6;
                const int d = (c - 1024) & 63;
                bf16_t pk[4];
#pragma unroll
                for (int rg = 0; rg < 4; ++rg) pk[rg] = (bf16_t)acc[i][j][rg];
                bf16_t* dst = vT + ((size_t)(b * NHEAD + h) * HDIM + d) * SEQ
                              + chunkbase + pbase;
                *(int2*)dst = *(int2*)pk;
            }
        }
    }
}

// --------------------------------------------------------------------------
// Per-head RMSNorm + RoPE for Q and K in one launch.  One wave per (row,head).
//   Qp/Kp are compact [8192][1024]; q gets 1/8 scale folded in.
// --------------------------------------------------------------------------
__global__ __launch_bounds__(256)
void norm_rope2(const bf16_t* __restrict__ Qp, const bf16_t* __restrict__ Kp,
                const int* __restrict__ tpos, const int* __restrict__ spos,
                const float* __restrict__ qw, const float* __restrict__ kw,
                bf16_t* __restrict__ qb, bf16_t* __restrict__ kbuf)
{
    const int lane = threadIdx.x & 63;
    const int wv   = threadIdx.x >> 6;
    int gid = blockIdx.x * 4 + wv;          // 0 .. 262143
    const bool isK = gid >= 131072;
    if (isK) gid -= 131072;
    const bf16_t* X   = isK ? Kp : Qp;
    const int*   pos  = isK ? spos : tpos;
    const float* w    = isK ? kw : qw;
    bf16_t*      outp = isK ? kbuf : qb;
    const float scale = isK ? 1.0f : 0.125f;

    const int row  = gid >> 4;
    const int head = gid & 15;
    const int bb   = row >> 11;
    const int ss_i = row & 2047;

    float x = (float)X[(size_t)row * 1024 + head * HDIM + lane];
    float ss = x * x;
#pragma unroll
    for (int off = 32; off; off >>= 1) ss += __shfl_xor(ss, off, 64);
    float xn = x * rsqrtf(ss * (1.f / 64.f) + RMS_EPS) * w[lane];

    const int p = pos[row];
    const int j = lane & 31;
    const float inv_freq = exp2f(-(float)j * LOG2_10000_DIV32);
    const float ang = (float)p * inv_freq;
    float sv, cv;
    sincosf(ang, &sv, &cv);
    const float other = __shfl_xor(xn, 32, 64);
    const float res = (lane < 32) ? (xn * cv - other * sv)
                                  : (xn * cv + other * sv);
    outp[((size_t)(bb * NHEAD + head) * SEQ + ss_i) * HDIM + lane] =
        (bf16_t)(res * scale);
}

// --------------------------------------------------------------------------
// Flash attention, fixed-max softmax, register-resident P.
//   S^T tiles: S'[m][q] = mfma(A=K-frag, B=Q-frag) -> C/D row=m, col=q.
//   P = exp(S') packed in-lane into the B-frag of O^T = mfma(A=V^T, B=P^T):
//   the k(m) permutation is baked into vT's storage order, so A and B agree.
//   m-chunk 128, block = 128 q-rows (4 waves x 2 q-tiles of 16).
// --------------------------------------------------------------------------
__global__ __launch_bounds__(256)
void attn(const bf16_t* __restrict__ q, const bf16_t* __restrict__ k,
          const bf16_t* __restrict__ vT, bf16_t* __restrict__ xo)
{
    __shared__ bf16_t Ks[128 * 64];       // [m][d], XOR-swizzled (8 slots)
    __shared__ bf16_t Vs[64 * 128];       // [d][m'], XOR-swizzled (16 slots)

    const int q0   = blockIdx.x * 128;
    const int h    = blockIdx.y;
    const int b    = blockIdx.z;
    const int bh   = b * NHEAD + h;
    const int tid  = threadIdx.x;
    const int lane = tid & 63;
    const int wv   = tid >> 6;
    const int lr   = lane & 15;
    const int quad = lane >> 4;

    const bf16_t* kb = k  + (size_t)bh * SEQ * HDIM;
    const bf16_t* vb = vT + (size_t)bh * HDIM * SEQ;

    // Q fragments (B-operand: b[n=q-row=lr][k=d=quad*8+j]), 2 q-tiles x 2 d-halves
    bf16x8 aq[2][2];
#pragma unroll
    for (int t = 0; t < 2; ++t) {
        const bf16_t* qp = q + ((size_t)bh * SEQ + q0 + wv * 32 + t * 16 + lr) * HDIM;
        aq[t][0] = *(const bf16x8*)(qp + quad * 8);
        aq[t][1] = *(const bf16x8*)(qp + 32 + quad * 8);
    }

    // staging descriptors: Ks 4 DMAs/wave (8 rows each), Vs 4 DMAs/wave (4 rows)
    size_t koff[4], voff[4];
    bf16_t *klp[4], *vlp[4];
#pragma unroll
    for (int t = 0; t < 4; ++t) {
        const int rbk = wv * 32 + t * 8;
        const int rk  = rbk + (lane >> 3);
        const int gk  = (lane & 7) ^ (rk & 7);
        koff[t] = (size_t)rk * HDIM + gk * 8;
        klp[t]  = Ks + rbk * 64;
        const int rbv = wv * 16 + t * 4;
        const int rv  = rbv + (lane >> 4);
        const int gv  = (lane & 15) ^ (rv & 15);
        voff[t] = (size_t)rv * SEQ + gv * 8;
        vlp[t]  = Vs + rbv * 128;
    }

    f32x4 zero4 = {0.f, 0.f, 0.f, 0.f};
    f32x4 o[2][4];                        // O^T acc: [q-tile][d-tile]
    float lsum[2] = {0.f, 0.f};
#pragma unroll
    for (int t = 0; t < 2; ++t)
#pragma unroll
        for (int dt = 0; dt < 4; ++dt) o[t][dt] = zero4;

    for (int m0 = 0; m0 < SEQ; m0 += 128) {
#pragma unroll
        for (int t = 0; t < 4; ++t) {
            async16(kb + (size_t)m0 * HDIM + koff[t], klp[t]);
            async16(vb + voff[t] + m0, vlp[t]);
        }
        __syncthreads();

#pragma unroll
        for (int ksm = 0; ksm < 4; ++ksm) {
            // --- two 16-m S^T subtiles -> exp'd P values in registers ---
            float pe[2][8];
#pragma unroll
            for (int half = 0; half < 2; ++half) {
                const int mt = ksm * 2 + half;
                f32x4 s0 = zero4, s1 = zero4;
#pragma unroll
                for (int ksd = 0; ksd < 2; ++ksd) {
                    bf16x8 ak = *(const bf16x8*)&Ks[(mt * 16 + lr) * 64 +
                                    (((ksd * 4 + quad) ^ (lr & 7)) * 8)];
                    s0 = __builtin_amdgcn_mfma_f32_16x16x32_bf16(ak, aq[0][ksd], s0, 0, 0, 0);
                    s1 = __builtin_amdgcn_mfma_f32_16x16x32_bf16(ak, aq[1][ksd], s1, 0, 0, 0);
                }
#pragma unroll
                for (int r = 0; r < 4; ++r) {
                    const float p0 = __expf(s0[r]);
                    const float p1 = __expf(s1[r]);
                    lsum[0] += p0; lsum[1] += p1;
                    pe[0][half * 4 + r] = p0;
                    pe[1][half * 4 + r] = p1;
                }
            }
            // --- pack P fragments (B-operand of PV, k-order = vT's m-perm) ---
            bf16x8 bp0, bp1;
#pragma unroll
            for (int idx = 0; idx < 8; ++idx) {
                bp0[idx] = (bf16_t)pe[0][idx];
                bp1[idx] = (bf16_t)pe[1][idx];
            }
            // --- PV: O^T += V^T * P^T ---
#pragma unroll
            for (int dt = 0; dt < 4; ++dt) {
                bf16x8 av = *(const bf16x8*)&Vs[(dt * 16 + lr) * 128 +
                                (((ksm * 4 + quad) ^ lr) * 8)];
                o[0][dt] = __builtin_amdgcn_mfma_f32_16x16x32_bf16(av, bp0, o[0][dt], 0, 0, 0);
                o[1][dt] = __builtin_amdgcn_mfma_f32_16x16x32_bf16(av, bp1, o[1][dt], 0, 0, 0);
            }
        }
        __syncthreads();
    }

    // row-sum: per-lane partial (q=lr) reduced across the 4 quads
#pragma unroll
    for (int t = 0; t < 2; ++t) {
        lsum[t] += __shfl_xor(lsum[t], 16, 64);
        lsum[t] += __shfl_xor(lsum[t], 32, 64);
        lsum[t] = 1.f / lsum[t];
    }

    // O^T C/D: row=d=quad*4+rg, col=q=lr  -> 4 consecutive d per lane: 8B stores
#pragma unroll
    for (int t = 0; t < 2; ++t)
#pragma unroll
        for (int dt = 0; dt < 4; ++dt) {
            bf16_t pk[4];
#pragma unroll
            for (int rg = 0; rg < 4; ++rg)
                pk[rg] = (bf16_t)(o[t][dt][rg] * lsum[t]);
            bf16_t* dst = xo + ((size_t)b * SEQ + q0 + wv * 32 + t * 16 + lr) * DIMM
                          + h * HDIM + dt * 16 + quad * 4;
            *(int2*)dst = *(int2*)pk;
        }
}

// --------------------------------------------------------------------------
extern "C" void kernel_launch(void* const* d_in, const int* in_sizes, int n_in,
                              void* d_out, int out_size, void* d_ws, size_t ws_size,
                              hipStream_t stream)
{
    const float* tgt  = (const float*)d_in[0];
    const float* src  = (const float*)d_in[1];
    const int*   tpos = (const int*)d_in[2];
    const int*   spos = (const int*)d_in[3];
    const float* Wq   = (const float*)d_in[4];
    const float* Wkv  = (const float*)d_in[5];
    const float* Wo   = (const float*)d_in[6];
    const float* qw   = (const float*)d_in[7];
    const float* kw   = (const float*)d_in[8];
    float* out = (float*)d_out;

    // workspace layout — 104 MB with buffer reuse
    char* ws = (char*)d_ws;
    const size_t MB = 1024 * 1024;
    bf16_t* Wq_t  = (bf16_t*)(ws + 0 * MB);    //  2 MB
    bf16_t* Wkv_t = (bf16_t*)(ws + 2 * MB);    //  4 MB
    bf16_t* Wo_t  = (bf16_t*)(ws + 6 * MB);    //  2 MB
    bf16_t* tgtb  = (bf16_t*)(ws + 8 * MB);    // 16 MB (dead after Q gemm)
    bf16_t* qb    = (bf16_t*)(ws + 8 * MB);    //   ... reused: q [b,h,n,64]
    bf16_t* srcb  = (bf16_t*)(ws + 24 * MB);   // 16 MB (dead after KV gemm)
    bf16_t* xb    = (bf16_t*)(ws + 24 * MB);   //   ... reused: attn out
    bf16_t* Qp    = (bf16_t*)(ws + 40 * MB);   // 16 MB
    bf16_t* Kp    = (bf16_t*)(ws + 56 * MB);   // 16 MB (compact K proj)
    bf16_t* kbuf  = (bf16_t*)(ws + 72 * MB);   // 16 MB
    bf16_t* vT    = (bf16_t*)(ws + 88 * MB);   // 16 MB (m-permuted V^T)

    // fp32 -> bf16 activations (one launch)
    cast2<<<8192, 256, 0, stream>>>(tgt, src, tgtb, srcb);

    // weight transposes (one launch)
    transpose3<<<4096, 256, 0, stream>>>(Wq, Wkv, Wo, Wq_t, Wkv_t, Wo_t);

    // projections; KV epilogue writes Kp compact + vT permuted (v_trans gone)
    gemm128<true><<<dim3(8, 64),  256, 0, stream>>>(tgtb, Wq_t, Qp, NROWS, 1024, 1024);
    gemm_kv<<<dim3(16, 64), 256, 0, stream>>>(srcb, Wkv_t, Kp, vT);

    // rmsnorm + rope for q and k (one launch; q gets 1/8 scale)
    norm_rope2<<<65536, 256, 0, stream>>>(Qp, Kp, tpos, spos, qw, kw, qb, kbuf);

    // flash attention
    attn<<<dim3(16, NHEAD, NB), 256, 0, stream>>>(qb, kbuf, vT, xb);

    // output projection (fp32 out)
    gemm128<false><<<dim3(8, 64), 256, 0, stream>>>(xb, Wo_t, out, NROWS, 1024, 1024);
}

// Round 4
// 360.362 us; speedup vs baseline: 1.5777x; 1.0313x over previous
//
#include <hip/hip_runtime.h>

// ---------------------------------------------------------------------------
// Attention_42674795053784 : cross-attention forward on MI355X (gfx950)
// R4: attn 4 q-tiles/wave (LDS reads halved per MFMA), exp2-folded softmax,
//     RMSNorm+RoPE fused into Q/KV GEMM epilogues (norm_rope kernel deleted).
// ---------------------------------------------------------------------------

typedef __bf16 bf16_t;
typedef __bf16 bf16x8 __attribute__((ext_vector_type(8)));
typedef float  f32x4  __attribute__((ext_vector_type(4)));

#define DIMM   1024
#define NHEAD  16
#define HDIM   64
#define NB     4
#define SEQ    2048
#define NROWS  (NB * SEQ)             // 8192
#define RMS_EPS 1.1920929e-07f
#define LOG2_10000_DIV32 0.4152410118609203f
// q scale: (1/8) * log2(e) so attn can use exp2 directly
#define QSCALE 0.18033688011112042f

// async global->LDS, 16B per lane; lds dest = base + lane*16 (wave-uniform base)
__device__ __forceinline__ void async16(const bf16_t* g, bf16_t* l) {
    __builtin_amdgcn_global_load_lds(
        (const __attribute__((address_space(1))) void*)g,
        (__attribute__((address_space(3))) void*)l, 16, 0, 0);
}

// --------------------------------------------------------------------------
// fp32 -> bf16 cast for tgt and src in one launch (8 elems/thread)
// --------------------------------------------------------------------------
__global__ __launch_bounds__(256)
void cast2(const float* __restrict__ tgt, const float* __restrict__ src,
           bf16_t* __restrict__ tgtb, bf16_t* __restrict__ srcb)
{
    int bid = blockIdx.x;
    const float* x;
    bf16_t* y;
    if (bid < 4096) { x = tgt; y = tgtb; }
    else            { bid -= 4096; x = src; y = srcb; }
    const size_t i = ((size_t)bid * 256 + threadIdx.x) * 8;
    float4 f0 = ((const float4*)(x + i))[0];
    float4 f1 = ((const float4*)(x + i))[1];
    bf16_t v[8];
    v[0] = (bf16_t)f0.x; v[1] = (bf16_t)f0.y; v[2] = (bf16_t)f0.z; v[3] = (bf16_t)f0.w;
    v[4] = (bf16_t)f1.x; v[5] = (bf16_t)f1.y; v[6] = (bf16_t)f1.z; v[7] = (bf16_t)f1.w;
    *(int4*)(y + i) = *(int4*)v;
}

// --------------------------------------------------------------------------
// All three weight transposes (fp32 [K][N] -> bf16 [N][K]) in one launch
// --------------------------------------------------------------------------
__global__ __launch_bounds__(256)
void transpose3(const float* __restrict__ Wq, const float* __restrict__ Wkv,
                const float* __restrict__ Wo, bf16_t* __restrict__ Wq_t,
                bf16_t* __restrict__ Wkv_t, bf16_t* __restrict__ Wo_t)
{
    __shared__ float t[32][33];
    int bid = blockIdx.x;
    const float* W; bf16_t* Wt; int N, nx;
    if (bid < 1024)      { W = Wq;  Wt = Wq_t;  N = 1024; nx = 32; }
    else if (bid < 3072) { bid -= 1024; W = Wkv; Wt = Wkv_t; N = 2048; nx = 64; }
    else                 { bid -= 3072; W = Wo;  Wt = Wo_t;  N = 1024; nx = 32; }
    const int K  = 1024;
    const int n0 = (bid % nx) * 32;
    const int k0 = (bid / nx) * 32;
    const int tx = threadIdx.x & 31;
    const int ty = threadIdx.x >> 5;
#pragma unroll
    for (int i = ty; i < 32; i += 8)
        t[i][tx] = W[(size_t)(k0 + i) * N + n0 + tx];
    __syncthreads();
#pragma unroll
    for (int i = ty; i < 32; i += 8)
        Wt[(size_t)(n0 + i) * K + k0 + tx] = (bf16_t)t[tx][i];
}

// --------------------------------------------------------------------------
// Shared GEMM main loop (m97-style): acc = A[128 rows] * Bt[128 rows]^T
// --------------------------------------------------------------------------
#define GEMM_MAIN_LOOP(A_, Bt_, K_)                                           \
    __shared__ bf16_t As[128 * 64];                                           \
    __shared__ bf16_t Bs[128 * 64];                                           \
    const int tid  = threadIdx.x;                                             \
    const int lane = tid & 63;                                                \
    const int wave = tid >> 6;                                                \
    const int wm   = (wave >> 1) * 64;                                        \
    const int wn   = (wave & 1) * 64;                                         \
    const int lr   = lane & 15;                                               \
    const int quad = lane >> 4;                                               \
    {                                                                         \
        const int srow = lane >> 3;                                           \
        const int sslot = lane & 7;                                           \
        size_t aoff[4], boff[4];                                              \
        bf16_t *alp[4], *blp[4];                                              \
        _Pragma("unroll")                                                     \
        for (int t = 0; t < 4; ++t) {                                         \
            const int rb = wave * 32 + t * 8;                                 \
            const int r  = rb + srow;                                         \
            const int g  = sslot ^ (r & 7);                                   \
            aoff[t] = (size_t)(bm + r) * (K_) + g * 8;                        \
            boff[t] = (size_t)(bn + r) * (K_) + g * 8;                        \
            alp[t]  = As + rb * 64;                                           \
            blp[t]  = Bs + rb * 64;                                           \
        }                                                                     \
        for (int k0 = 0; k0 < (K_); k0 += 64) {                               \
            _Pragma("unroll")                                                 \
            for (int t = 0; t < 4; ++t) {                                     \
                async16((A_)  + aoff[t] + k0, alp[t]);                        \
                async16((Bt_) + boff[t] + k0, blp[t]);                        \
            }                                                                 \
            __syncthreads();                                                  \
            _Pragma("unroll")                                                 \
            for (int ks = 0; ks < 2; ++ks) {                                  \
                bf16x8 af[4], bfr[4];                                         \
                _Pragma("unroll")                                             \
                for (int i = 0; i < 4; ++i)                                   \
                    af[i] = *(const bf16x8*)&As[(wm + i * 16 + lr) * 64 +     \
                                (((ks * 4 + quad) ^ (lr & 7)) * 8)];          \
                _Pragma("unroll")                                             \
                for (int j = 0; j < 4; ++j)                                   \
                    bfr[j] = *(const bf16x8*)&Bs[(wn + j * 16 + lr) * 64 +    \
                                (((ks * 4 + quad) ^ (lr & 7)) * 8)];          \
                _Pragma("unroll")                                             \
                for (int i = 0; i < 4; ++i)                                   \
                    _Pragma("unroll")                                         \
                    for (int j = 0; j < 4; ++j)                               \
                        acc[i][j] = __builtin_amdgcn_mfma_f32_16x16x32_bf16(  \
                            af[i], bfr[j], acc[i][j], 0, 0, 0);               \
            }                                                                 \
            __syncthreads();                                                  \
        }                                                                     \
    }

// Fused per-head RMSNorm + RoPE epilogue (wave's 64 cols == one head).
//   acc[i][j][rg]: row = bm+wm+i*16+quad*4+rg, col(head-d) = j*16+lr.
//   RMS: sum_j acc^2, shuffle-reduce over lr (16 lanes).
//   RoPE pair (d, d+32) = regs (j, j+2) in-lane.
__device__ __forceinline__ void norm_rope_store(
    f32x4 acc[4][4], const int* __restrict__ pos, const float* __restrict__ w,
    bf16_t* __restrict__ dstbase, int bm, int wm, int head,
    int lr, int quad, float oscale)
{
    float w0 = w[lr], w1 = w[16 + lr], w2 = w[32 + lr], w3 = w[48 + lr];
    const float invf0 = exp2f(-(float)lr * LOG2_10000_DIV32);
    const float invf1 = exp2f(-(float)(lr + 16) * LOG2_10000_DIV32);
#pragma unroll
    for (int i = 0; i < 4; ++i) {
        const int gr = bm + wm + i * 16 + quad * 4;
        int4 pos4 = *(const int4*)&pos[gr];
#pragma unroll
        for (int rg = 0; rg < 4; ++rg) {
            float x0 = acc[i][0][rg], x1 = acc[i][1][rg];
            float x2 = acc[i][2][rg], x3 = acc[i][3][rg];
            float ssum = x0 * x0 + x1 * x1 + x2 * x2 + x3 * x3;
#pragma unroll
            for (int off = 1; off < 16; off <<= 1)
                ssum += __shfl_xor(ssum, off, 64);
            const float rn = rsqrtf(ssum * (1.f / 64.f) + RMS_EPS);
            x0 *= rn * w0; x1 *= rn * w1; x2 *= rn * w2; x3 *= rn * w3;
            const float p  = (float)((&pos4.x)[rg]);
            const float a0 = p * invf0, a1 = p * invf1;
            const float s0 = __sinf(a0), c0 = __cosf(a0);
            const float s1 = __sinf(a1), c1 = __cosf(a1);
            const int row = gr + rg;                  // 0..8191
            const int bb = row >> 11, si = row & 2047;
            bf16_t* dst = dstbase +
                ((size_t)(bb * NHEAD + head) * SEQ + si) * HDIM;
            dst[lr]      = (bf16_t)((x0 * c0 - x2 * s0) * oscale);
            dst[16 + lr] = (bf16_t)((x1 * c1 - x3 * s1) * oscale);
            dst[32 + lr] = (bf16_t)((x2 * c0 + x0 * s0) * oscale);
            dst[48 + lr] = (bf16_t)((x3 * c1 + x1 * s1) * oscale);
        }
    }
}

// --------------------------------------------------------------------------
// Q GEMM with fused RMSNorm+RoPE epilogue -> qb [b,h,n,64], scale folded.
// --------------------------------------------------------------------------
__global__ __launch_bounds__(256)
void gemm_q(const bf16_t* __restrict__ A, const bf16_t* __restrict__ Bt,
            const int* __restrict__ tpos, const float* __restrict__ qw,
            bf16_t* __restrict__ qb)
{
    const int bm = blockIdx.y * 128;
    const int bn = blockIdx.x * 128;
    f32x4 acc[4][4] = {};
    GEMM_MAIN_LOOP(A, Bt, 1024)
    const int head = (bn + wn) >> 6;
    norm_rope_store(acc, tpos, qw, qb, bm, wm, head, lr, quad, QSCALE);
}

// --------------------------------------------------------------------------
// KV GEMM: K cols (<1024) -> fused RMSNorm+RoPE -> kbuf [b,h,m,64];
//          V cols (>=1024) -> m-permuted vT [(b,h)][d][m'] (PV B-frag order).
// --------------------------------------------------------------------------
__global__ __launch_bounds__(256)
void gemm_kv(const bf16_t* __restrict__ A, const bf16_t* __restrict__ Bt,
             const int* __restrict__ spos, const float* __restrict__ kw,
             bf16_t* __restrict__ kbuf, bf16_t* __restrict__ vT)
{
    const int bm = blockIdx.y * 128;
    const int bn = blockIdx.x * 128;
    f32x4 acc[4][4] = {};
    GEMM_MAIN_LOOP(A, Bt, 1024)

    if (bn < 1024) {       // K projection
        const int head = (bn + wn) >> 6;
        norm_rope_store(acc, spos, kw, kbuf, bm, wm, head, lr, quad, 1.0f);
    } else {               // V projection, m-permuted direct to vT
#pragma unroll
        for (int i = 0; i < 4; ++i) {
            const int M0 = bm + wm + i * 16;
            const int b  = M0 >> 11;
            const int mB = M0 & 2047;
            const int chunkbase = mB & ~127;
            const int ksm  = (mB >> 5) & 3;
            const int bit4 = (mB >> 4) & 1;
            const int pbase = (ksm * 4 + quad) * 8 + bit4 * 4;
#pragma unroll
            for (int j = 0; j < 4; ++j) {
                const int c = bn + wn + j * 16 + lr - 1024;
                const int h = c >> 6;
                const int d = c & 63;
                bf16_t pk[4];
#pragma unroll
                for (int rg = 0; rg < 4; ++rg) pk[rg] = (bf16_t)acc[i][j][rg];
                bf16_t* dst = vT + ((size_t)(b * NHEAD + h) * HDIM + d) * SEQ
                              + chunkbase + pbase;
                *(int2*)dst = *(int2*)pk;
            }
        }
    }
}

// --------------------------------------------------------------------------
// Plain GEMM for the output projection (fp32 out).
// --------------------------------------------------------------------------
__global__ __launch_bounds__(256)
void gemm_o(const bf16_t* __restrict__ A, const bf16_t* __restrict__ Bt,
            float* __restrict__ Cp)
{
    const int bm = blockIdx.y * 128;
    const int bn = blockIdx.x * 128;
    f32x4 acc[4][4] = {};
    GEMM_MAIN_LOOP(A, Bt, 1024)
#pragma unroll
    for (int i = 0; i < 4; ++i)
#pragma unroll
        for (int j = 0; j < 4; ++j) {
            const int r0 = bm + wm + i * 16 + quad * 4;
            const int c  = bn + wn + j * 16 + lr;
#pragma unroll
            for (int rg = 0; rg < 4; ++rg)
                Cp[(size_t)(r0 + rg) * 1024 + c] = acc[i][j][rg];
        }
}

// --------------------------------------------------------------------------
// Flash attention, fixed-max softmax (exp2 domain), register-resident P.
//   Block = 128 threads (2 waves), 128 q-rows; each wave: 4 q-tiles (64 q).
//   m-chunk 128.  S^T = mfma(K-frag, Q-frag); P packs in-lane into the PV
//   B-frag (k-order baked into vT); O^T = mfma(V^T-frag, P-frag).
// --------------------------------------------------------------------------
__global__ __launch_bounds__(128)
void attn(const bf16_t* __restrict__ q, const bf16_t* __restrict__ k,
          const bf16_t* __restrict__ vT, bf16_t* __restrict__ xo)
{
    __shared__ bf16_t Ks[128 * 64];       // [m][d], XOR-swizzled (8 slots)
    __shared__ bf16_t Vs[64 * 128];       // [d][m'], XOR-swizzled (16 slots)

    const int q0   = blockIdx.x * 128;
    const int h    = blockIdx.y;
    const int b    = blockIdx.z;
    const int bh   = b * NHEAD + h;
    const int tid  = threadIdx.x;
    const int lane = tid & 63;
    const int wv   = tid >> 6;            // 0..1
    const int lr   = lane & 15;
    const int quad = lane >> 4;

    const bf16_t* kb = k  + (size_t)bh * SEQ * HDIM;
    const bf16_t* vb = vT + (size_t)bh * HDIM * SEQ;

    // Q fragments (B-operand), 4 q-tiles x 2 d-halves
    bf16x8 aq[4][2];
#pragma unroll
    for (int t = 0; t < 4; ++t) {
        const bf16_t* qp = q + ((size_t)bh * SEQ + q0 + wv * 64 + t * 16 + lr) * HDIM;
        aq[t][0] = *(const bf16x8*)(qp + quad * 8);
        aq[t][1] = *(const bf16x8*)(qp + 32 + quad * 8);
    }

    // staging: 8 DMAs/wave each for Ks (8 rows/DMA) and Vs (4 rows/DMA)
    size_t koff[8], voff[8];
    bf16_t *klp[8], *vlp[8];
#pragma unroll
    for (int t = 0; t < 8; ++t) {
        const int rbk = wv * 64 + t * 8;
        const int rk  = rbk + (lane >> 3);
        const int gk  = (lane & 7) ^ (rk & 7);
        koff[t] = (size_t)rk * HDIM + gk * 8;
        klp[t]  = Ks + rbk * 64;
        const int rbv = wv * 32 + t * 4;
        const int rv  = rbv + (lane >> 4);
        const int gv  = (lane & 15) ^ (rv & 15);
        voff[t] = (size_t)rv * SEQ + gv * 8;
        vlp[t]  = Vs + rbv * 128;
    }

    f32x4 zero4 = {0.f, 0.f, 0.f, 0.f};
    f32x4 o[4][4];                        // [q-tile][d-tile]
    float lsum[4] = {0.f, 0.f, 0.f, 0.f};
#pragma unroll
    for (int t = 0; t < 4; ++t)
#pragma unroll
        for (int dt = 0; dt < 4; ++dt) o[t][dt] = zero4;

    for (int m0 = 0; m0 < SEQ; m0 += 128) {
#pragma unroll
        for (int t = 0; t < 8; ++t) {
            async16(kb + (size_t)m0 * HDIM + koff[t], klp[t]);
            async16(vb + voff[t] + m0, vlp[t]);
        }
        __syncthreads();

#pragma unroll
        for (int ksm = 0; ksm < 4; ++ksm) {
            bf16x8 bp[4];
#pragma unroll
            for (int half = 0; half < 2; ++half) {
                const int mt = ksm * 2 + half;
                f32x4 s[4] = {zero4, zero4, zero4, zero4};
#pragma unroll
                for (int ksd = 0; ksd < 2; ++ksd) {
                    bf16x8 ak = *(const bf16x8*)&Ks[(mt * 16 + lr) * 64 +
                                    (((ksd * 4 + quad) ^ (lr & 7)) * 8)];
#pragma unroll
                    for (int t = 0; t < 4; ++t)
                        s[t] = __builtin_amdgcn_mfma_f32_16x16x32_bf16(
                            ak, aq[t][ksd], s[t], 0, 0, 0);
                }
#pragma unroll
                for (int t = 0; t < 4; ++t)
#pragma unroll
                    for (int r = 0; r < 4; ++r) {
                        const float p = exp2f(s[t][r]);
                        lsum[t] += p;
                        bp[t][half * 4 + r] = (bf16_t)p;
                    }
            }
#pragma unroll
            for (int dt = 0; dt < 4; ++dt) {
                bf16x8 av = *(const bf16x8*)&Vs[(dt * 16 + lr) * 128 +
                                (((ksm * 4 + quad) ^ lr) * 8)];
#pragma unroll
                for (int t = 0; t < 4; ++t)
                    o[t][dt] = __builtin_amdgcn_mfma_f32_16x16x32_bf16(
                        av, bp[t], o[t][dt], 0, 0, 0);
            }
        }
        __syncthreads();
    }

    // row-sum: per-lane partial (q=lr) reduced across the 4 quads
#pragma unroll
    for (int t = 0; t < 4; ++t) {
        lsum[t] += __shfl_xor(lsum[t], 16, 64);
        lsum[t] += __shfl_xor(lsum[t], 32, 64);
        lsum[t] = 1.f / lsum[t];
    }

    // O^T C/D: row=d=quad*4+rg, col=q=lr -> 4 consecutive d: 8B stores
#pragma unroll
    for (int t = 0; t < 4; ++t)
#pragma unroll
        for (int dt = 0; dt < 4; ++dt) {
            bf16_t pk[4];
#pragma unroll
            for (int rg = 0; rg < 4; ++rg)
                pk[rg] = (bf16_t)(o[t][dt][rg] * lsum[t]);
            bf16_t* dst = xo + ((size_t)b * SEQ + q0 + wv * 64 + t * 16 + lr) * DIMM
                          + h * HDIM + dt * 16 + quad * 4;
            *(int2*)dst = *(int2*)pk;
        }
}

// --------------------------------------------------------------------------
extern "C" void kernel_launch(void* const* d_in, const int* in_sizes, int n_in,
                              void* d_out, int out_size, void* d_ws, size_t ws_size,
                              hipStream_t stream)
{
    const float* tgt  = (const float*)d_in[0];
    const float* src  = (const float*)d_in[1];
    const int*   tpos = (const int*)d_in[2];
    const int*   spos = (const int*)d_in[3];
    const float* Wq   = (const float*)d_in[4];
    const float* Wkv  = (const float*)d_in[5];
    const float* Wo   = (const float*)d_in[6];
    const float* qw   = (const float*)d_in[7];
    const float* kw   = (const float*)d_in[8];
    float* out = (float*)d_out;

    // workspace layout — 88 MB with buffer reuse
    char* ws = (char*)d_ws;
    const size_t MB = 1024 * 1024;
    bf16_t* Wq_t  = (bf16_t*)(ws + 0 * MB);    //  2 MB
    bf16_t* Wkv_t = (bf16_t*)(ws + 2 * MB);    //  4 MB
    bf16_t* Wo_t  = (bf16_t*)(ws + 6 * MB);    //  2 MB
    bf16_t* tgtb  = (bf16_t*)(ws + 8 * MB);    // 16 MB
    bf16_t* srcb  = (bf16_t*)(ws + 24 * MB);   // 16 MB (dead after gemm_kv)
    bf16_t* xb    = (bf16_t*)(ws + 24 * MB);   //   ... reused: attn out
    bf16_t* qb    = (bf16_t*)(ws + 40 * MB);   // 16 MB  [b,h,n,64]
    bf16_t* kbuf  = (bf16_t*)(ws + 56 * MB);   // 16 MB  [b,h,m,64]
    bf16_t* vT    = (bf16_t*)(ws + 72 * MB);   // 16 MB  [b,h,64,m'] permuted

    // fp32 -> bf16 activations (one launch)
    cast2<<<8192, 256, 0, stream>>>(tgt, src, tgtb, srcb);

    // weight transposes (one launch)
    transpose3<<<4096, 256, 0, stream>>>(Wq, Wkv, Wo, Wq_t, Wkv_t, Wo_t);

    // projections with fused norm+rope epilogues
    gemm_q <<<dim3(8, 64),  256, 0, stream>>>(tgtb, Wq_t,  tpos, qw, qb);
    gemm_kv<<<dim3(16, 64), 256, 0, stream>>>(srcb, Wkv_t, spos, kw, kbuf, vT);

    // flash attention (exp2-domain fixed-max softmax)
    attn<<<dim3(16, NHEAD, NB), 128, 0, stream>>>(qb, kbuf, vT, xb);

    // output projection (fp32 out)
    gemm_o<<<dim3(8, 64), 256, 0, stream>>>(xb, Wo_t, out);
}